// Round 2
// baseline (17960.091 us; speedup 1.0000x reference)
//
#include <hip/hip_runtime.h>
#include <math.h>

#define T_LEN 4096
#define EDIM  256
#define HDIM  512
#define NTAGS 50
#define SENTW 0xFFFFFFFFu

__device__ __forceinline__ float sigm(float x) {
    return __builtin_amdgcn_rcpf(1.0f + __expf(-x));
}
__device__ __forceinline__ float tanh_fast(float x) {
    float e = __expf(2.0f * x);                       // x>>0 -> inf -> rcp=0 -> 1; x<<0 -> 0 -> -1
    return 1.0f - 2.0f * __builtin_amdgcn_rcpf(e + 1.0f);
}
__device__ __forceinline__ float u2f(unsigned u) { union { unsigned i; float f; } v; v.i = u; return v.f; }
__device__ __forceinline__ float rdlane(float v, int l) {
    union { float f; int i; } a, r;
    a.f = v;
    r.i = __builtin_amdgcn_readlane(a.i, l);   // SGPR broadcast, VALU-only
    return r.f;
}
// Spin poll: sc0 bypasses L1 only -> served by the XCD-local L2, which the
// producer's PLAIN store updates (same XCD). Blocking (fine inside a spin).
__device__ __forceinline__ unsigned long long poll_l2(const unsigned long long* p) {
    unsigned long long r;
    asm volatile("global_load_dwordx2 %0, %1, off sc0\n\t"
                 "s_waitcnt vmcnt(0)"
                 : "=v"(r) : "v"(p) : "memory");
    return r;
}

// ---------------------------------------------------------------------------
// Persistent bidirectional LSTM scan (f32), data-as-flag sync, SGPR-broadcast
// matvec, XCD-concentrated (fwd on XCD0, bwd on XCD1; placement-independent
// correctness via scanner fallback + agent-scope mirror traffic).
//
// ROUND-2 sync protocol (the round-1 fix):
//  * Producer h-store is DUAL: (1) plain global_store (no sc bits) -> lands
//    in the producer XCD's L2; (2) agent-scope atomic store to the SAME
//    address -> write-through to L3 for cross-XCD visibility (fallback
//    consumers, out_gemm). The plain store is inline asm so DSE can't drop it.
//  * Consumer: FIRST sample = workgroup-scope atomic load (plain
//    global_load_dwordx2, non-blocking -> overlaps enext load + x-matvec;
//    the line is never L1-resident, stores are no-allocate). Spin = sc0
//    polls (local-L2-served, ~200cy) with every-8th agent-scope load for
//    guaranteed progress under arbitrary placement.
//  * pl padded to stride 65: finalize read was an 8-way bank conflict.
// ---------------------------------------------------------------------------
__global__ __launch_bounds__(256, 2) void lstm_scan(
    const int* __restrict__ sent, const float* __restrict__ emb,
    const float* __restrict__ Wih_f, const float* __restrict__ Whh_f,
    const float* __restrict__ bih_f, const float* __restrict__ bhh_f,
    const float* __restrict__ Wih_b, const float* __restrict__ Whh_b,
    const float* __restrict__ bih_b, const float* __restrict__ bhh_b,
    float* hsf, float* hsb, int* ctl)
{
    const int tid  = threadIdx.x;
    const int lane = tid & 63;
    const int wv   = tid >> 6;          // wave id = column block

    // ---- role assignment: ctl = [ctr[8] | claims[64] @+8 | percu[2][256] @+80]
    __shared__ int job_sh;
    if (tid == 0) {
        int* ctr    = ctl;
        int* claims = ctl + 8;
        int* percu  = ctl + 80;
        int xcd = __builtin_amdgcn_s_getreg((3 << 11) | (0 << 6) | 20) & 0xF;  // XCC_ID[3:0]
        int job = -1;
        if (xcd <= 1) {
            int cukey = __builtin_amdgcn_s_getreg((7 << 11) | (8 << 6) | 4) & 0xFF; // HW_ID[15:8]: CU/SH/SE
            if (atomicCAS(&percu[xcd * 256 + cukey], 0, 1) == 0) {   // one block per CU
                int rank = atomicAdd(&ctr[xcd], 1);
                if (rank < 32) {
                    int j = xcd * 32 + rank;                          // xcd0->fwd, xcd1->bwd
                    if (atomicCAS(&claims[j], 0, 1) == 0) job = j;
                }
            }
        }
        if (job < 0) {
            // scanner fallback: wait ~200us (s_memrealtime ~100 MHz), claim leftovers
            unsigned long long t0 = __builtin_amdgcn_s_memrealtime();
            while (__builtin_amdgcn_s_memrealtime() - t0 < 20000ull)
                __builtin_amdgcn_s_sleep(16);
            for (int j = 0; j < 64; ++j)
                if (atomicCAS(&claims[j], 0, 1) == 0) { job = j; break; }
        }
        job_sh = job;
    }
    __syncthreads();
    const int job = job_sh;
    if (job < 0) return;            // surplus block

    const int dir = job >> 5;
    const int g   = job & 31;

    const float* Wih = dir ? Wih_b : Wih_f;
    const float* Whh = dir ? Whh_b : Whh_f;
    const float* bih = dir ? bih_b : bih_f;
    const float* bhh = dir ? bhh_b : bhh_f;
    float* hs = dir ? hsb : hsf;

    const int q = lane >> 4;
    const int u = lane & 15;
    const int R = q * 512 + g * 16 + u;

    // W_hh cols [wv*128,+128) of row R -> 128 VGPRs.
    float wh[128];
    {
        const float* base = Whh + (size_t)R * HDIM + wv * 128;
        #pragma unroll
        for (int i = 0; i < 32; ++i) {
            float4 v = *(const float4*)(base + 4 * i);
            wh[4*i] = v.x; wh[4*i+1] = v.y; wh[4*i+2] = v.z; wh[4*i+3] = v.w;
        }
    }
    // W_ih cols [wv*64,+64) of row R -> 64 VGPRs.
    float wx[64];
    {
        const float* base = Wih + (size_t)R * EDIM + wv * 64;
        #pragma unroll
        for (int i = 0; i < 16; ++i) {
            float4 v = *(const float4*)(base + 4 * i);
            wx[4*i] = v.x; wx[4*i+1] = v.y; wx[4*i+2] = v.z; wx[4*i+3] = v.w;
        }
    }
    // Per-wave finalize biases: lanes 0..3 own unit uu = g*16 + wv*4 + lane.
    float bi = 0.f, bff = 0.f, bgg = 0.f, boo = 0.f;
    if (lane < 4) {
        int uu = g * 16 + wv * 4 + lane;
        bi  = bih[uu]        + bhh[uu];
        bff = bih[512 + uu]  + bhh[512 + uu];
        bgg = bih[1024 + uu] + bhh[1024 + uu];
        boo = bih[1536 + uu] + bhh[1536 + uu];
    }

    __shared__ float pl[2][260];        // stride 65: conflict-free finalize read
    float c_state = 0.0f;               // valid on lanes 0..3 of each wave

    // Embedding value pipeline: lane holds emb[sent[t]][wv*64 + lane].
    float ecur;
    {
        int t0 = dir ? (T_LEN - 1) : 0;
        ecur = emb[(size_t)sent[t0] * EDIM + wv * 64 + lane];
    }

    for (int s = 0; s < T_LEN; ++s) {
        const int t = dir ? (T_LEN - 1 - s) : s;

        // First poll sample: plain non-blocking load (workgroup scope ->
        // no sc bits), issued ASAP so it flies under enext + x-matvec.
        const unsigned long long* p = nullptr;
        unsigned long long v = 0;
        if (s > 0) {
            const int tp = dir ? (t + 1) : (t - 1);
            p = (const unsigned long long*)(hs + (size_t)tp * HDIM + wv * 128) + lane;
            v = __hip_atomic_load(p, __ATOMIC_RELAXED, __HIP_MEMORY_SCOPE_WORKGROUP);
        }
        // Prefetch next step's embedding value (h-independent).
        float enext = 0.0f;
        if (s + 1 < T_LEN) {
            int tn = dir ? (t - 1) : (t + 1);
            enext = emb[(size_t)sent[tn] * EDIM + wv * 64 + lane];
        }

        // x partial: 64 SGPR-broadcast MACs over 4 independent accumulators.
        float a0 = 0.f, a1 = 0.f, a2 = 0.f, a3 = 0.f;
        #pragma unroll
        for (int i = 0; i < 16; ++i) {
            a0 = fmaf(wx[4*i+0], rdlane(ecur, 4*i+0), a0);
            a1 = fmaf(wx[4*i+1], rdlane(ecur, 4*i+1), a1);
            a2 = fmaf(wx[4*i+2], rdlane(ecur, 4*i+2), a2);
            a3 = fmaf(wx[4*i+3], rdlane(ecur, 4*i+3), a3);
        }

        if (s > 0) {
            int k = 0;
            while (((unsigned)v == SENTW) || ((unsigned)(v >> 32) == SENTW)) {
                ++k;
                v = (k & 7) ? poll_l2(p)
                            : __hip_atomic_load(p, __ATOMIC_RELAXED, __HIP_MEMORY_SCOPE_AGENT);
            }
            float h0 = u2f((unsigned)v);
            float h1 = u2f((unsigned)(v >> 32));
            // h partial: 128 SGPR-broadcast MACs, 4 chains.
            #pragma unroll
            for (int i = 0; i < 32; ++i) {
                a0 = fmaf(wh[4*i+0], rdlane(h0, 2*i+0), a0);
                a1 = fmaf(wh[4*i+1], rdlane(h1, 2*i+0), a1);
                a2 = fmaf(wh[4*i+2], rdlane(h0, 2*i+1), a2);
                a3 = fmaf(wh[4*i+3], rdlane(h1, 2*i+1), a3);
            }
        }

        pl[s & 1][wv * 65 + lane] = (a0 + a1) + (a2 + a3);
        __syncthreads();

        // Wave-parallel finalize: wave wv handles units [g*16 + wv*4, +4).
        {
            const float* pb = pl[s & 1];
            const int idx = lane & 15;              // 4q + m over this wave's 4 units
            float val = pb[(lane >> 4) * 65 + (idx >> 2) * 16 + wv * 4 + (idx & 3)];
            val += __shfl_xor(val, 16, 64);         // reduce over column blocks
            val += __shfl_xor(val, 32, 64);
            const int m = lane & 3;
            float gi = __shfl(val, m,      64) + bi;
            float gf = __shfl(val, 4 + m,  64) + bff;
            float gg = __shfl(val, 8 + m,  64) + bgg;
            float go = __shfl(val, 12 + m, 64) + boo;
            if (lane < 4) {
                float iv = sigm(gi), fv = sigm(gf);
                float gv = tanh_fast(gg), ov = sigm(go);
                c_state = fv * c_state + iv * gv;
                float h = ov * tanh_fast(c_state);
                float* dst = hs + (size_t)t * HDIM + g * 16 + wv * 4 + lane;
                // (1) plain store -> XCD-local L2 (fast path for sc0 polls).
                asm volatile("global_store_dword %0, %1, off"
                             :: "v"(dst), "v"(h) : "memory");
                // (2) agent-scope mirror -> L3, for cross-XCD readers.
                __hip_atomic_store(dst, h, __ATOMIC_RELAXED, __HIP_MEMORY_SCOPE_AGENT);
            }
        }
        ecur = enext;
    }
}

// ---------------------------------------------------------------------------
// tag_space[t] = [hs_f[t] | hs_b[t]] @ W_out^T + b_out  (f32 out)
// ---------------------------------------------------------------------------
__global__ __launch_bounds__(256) void out_gemm(
    const float* __restrict__ hsf, const float* __restrict__ hsb,
    const float* __restrict__ Wout, const float* __restrict__ bout,
    float* __restrict__ out)
{
    const int t   = blockIdx.x;
    const int tid = threadIdx.x;
    __shared__ float h2[1024];

    if (tid < 128)
        *(float4*)(h2 + tid * 4) = *(const float4*)(hsf + (size_t)t * HDIM + tid * 4);
    else
        *(float4*)(h2 + 512 + (tid - 128) * 4) = *(const float4*)(hsb + (size_t)t * HDIM + (tid - 128) * 4);
    __syncthreads();

    const int wv = tid >> 6, lane = tid & 63;
    for (int tag = wv; tag < NTAGS; tag += 4) {
        const float4* wr = (const float4*)(Wout + (size_t)tag * (2 * HDIM));
        float p = 0.0f;
        #pragma unroll
        for (int c = lane; c < 256; c += 64) {
            float4 wv4 = wr[c];
            float4 hv  = *(const float4*)(h2 + c * 4);
            p += wv4.x * hv.x + wv4.y * hv.y + wv4.z * hv.z + wv4.w * hv.w;
        }
        p += __shfl_down(p, 32, 64);
        p += __shfl_down(p, 16, 64);
        p += __shfl_down(p, 8, 64);
        p += __shfl_down(p, 4, 64);
        p += __shfl_down(p, 2, 64);
        p += __shfl_down(p, 1, 64);
        if (lane == 0) out[(size_t)t * NTAGS + tag] = p + bout[tag];
    }
}

// ---------------------------------------------------------------------------
extern "C" void kernel_launch(void* const* d_in, const int* in_sizes, int n_in,
                              void* d_out, int out_size, void* d_ws, size_t ws_size,
                              hipStream_t stream)
{
    const int*   sent  = (const int*)d_in[0];
    const float* emb   = (const float*)d_in[1];
    const float* Wih_f = (const float*)d_in[2];
    const float* Whh_f = (const float*)d_in[3];
    const float* bih_f = (const float*)d_in[4];
    const float* bhh_f = (const float*)d_in[5];
    const float* Wih_b = (const float*)d_in[6];
    const float* Whh_b = (const float*)d_in[7];
    const float* bih_b = (const float*)d_in[8];
    const float* bhh_b = (const float*)d_in[9];
    const float* Wout  = (const float*)d_in[10];
    const float* bout  = (const float*)d_in[11];
    float* out = (float*)d_out;

    char* ws = (char*)d_ws;
    // Workspace: hsf [4096*512 f32] @ 0 (8 MiB), hsb @ 8 MiB. Both double as
    // sync flags: sentinel-fill with 0xFF (-NaN, never produced by o*tanh(c)).
    float* hsf = (float*)(ws);
    float* hsb = (float*)(ws + 8388608);
    hipMemsetAsync(ws, 0xFF, 16777216, stream);

    // Role-assignment control block (ctr/claims/percu), zero-initialized.
    int* ctl;
    if (ws_size >= 16777216 + 4096) ctl = (int*)(ws + 16777216);
    else                            ctl = (int*)((char*)d_out + out_size - 4096);
    hipMemsetAsync(ctl, 0, 4096, stream);

    lstm_scan<<<512, 256, 0, stream>>>(sent, emb,
                                       Wih_f, Whh_f, bih_f, bhh_f,
                                       Wih_b, Whh_b, bih_b, bhh_b,
                                       hsf, hsb, ctl);
    out_gemm<<<T_LEN, 256, 0, stream>>>(hsf, hsb, Wout, bout, out);
}

// Round 3
// 10889.206 us; speedup vs baseline: 1.6493x; 1.6493x over previous
//
#include <hip/hip_runtime.h>
#include <math.h>

#define T_LEN 4096
#define EDIM  256
#define HDIM  512
#define NTAGS 50
#define SENTW 0xFFFFFFFFu

__device__ __forceinline__ float sigm(float x) {
    return __builtin_amdgcn_rcpf(1.0f + __expf(-x));
}
__device__ __forceinline__ float tanh_fast(float x) {
    float e = __expf(2.0f * x);                       // x>>0 -> inf -> rcp=0 -> 1; x<<0 -> 0 -> -1
    return 1.0f - 2.0f * __builtin_amdgcn_rcpf(e + 1.0f);
}
__device__ __forceinline__ float u2f(unsigned u) { union { unsigned i; float f; } v; v.i = u; return v.f; }
__device__ __forceinline__ float rdlane(float v, int l) {
    union { float f; int i; } a, r;
    a.f = v;
    r.i = __builtin_amdgcn_readlane(a.i, l);   // SGPR broadcast, VALU-only
    return r.f;
}
// Agent-scope relaxed poll (bypasses L1+L2, serviced at the device coherence
// point). This is the ONLY load flavor proven (rounds 0-2) to observe
// progress; sc0/L2 shortcuts pin stale lines and never advance.
__device__ __forceinline__ unsigned long long pollA(const unsigned long long* p) {
    return __hip_atomic_load(p, __ATOMIC_RELAXED, __HIP_MEMORY_SCOPE_AGENT);
}
__device__ __forceinline__ bool bad2(unsigned long long v) {
    return ((unsigned)v == SENTW) || ((unsigned)(v >> 32) == SENTW);
}

// ---------------------------------------------------------------------------
// Persistent bidirectional LSTM scan (f32), data-as-flag sync, SGPR-broadcast
// matvec. Round-3 structure = round-0 skeleton (round-robin placement, pure
// agent-scope sync) + PIPELINED POLLING:
//   * Ring of 4 in-flight relaxed agent loads to the same flag word. Checking
//     only the oldest lets the backend emit counted s_waitcnt vmcnt(3); in
//     steady state the check gates the reissue, so the flag is sampled every
//     ~RT/4 cycles instead of every RT. This shrinks both the discovery tail
//     and the per-step max-over-32-producers jitter (the dominant cost seen
//     in round 0: 5200 cy/step vs ~450 cy VALU).
//   * Wave-parallel finalize (each wave finalizes 4 units; no serial wave-0
//     tail), 4 independent FMA chains, fast __expf/rcp activations.
//   * No XCD claiming / no sc0 polls / no dual stores (rounds 1-2 showed the
//     L2 fast path never observes agent-store progress on this part).
// 64 WGs x 256 threads: blocks 0..31 forward, 32..63 backward.
// WG g owns hidden units [g*16,+16) => 64 gate rows. lane = row:
//   q = lane>>4 (gate i,f,g,o), u = lane&15, R = q*512 + g*16 + u.
// Wave wv owns column block: W_hh cols [wv*128,+128), W_ih cols [wv*64,+64).
// ---------------------------------------------------------------------------
__global__ __launch_bounds__(256, 1) void lstm_scan(
    const int* __restrict__ sent, const float* __restrict__ emb,
    const float* __restrict__ Wih_f, const float* __restrict__ Whh_f,
    const float* __restrict__ bih_f, const float* __restrict__ bhh_f,
    const float* __restrict__ Wih_b, const float* __restrict__ Whh_b,
    const float* __restrict__ bih_b, const float* __restrict__ bhh_b,
    float* hsf, float* hsb)
{
    const int tid  = threadIdx.x;
    const int lane = tid & 63;
    const int wv   = tid >> 6;          // wave id = column block
    const int dir  = blockIdx.x >> 5;
    const int g    = blockIdx.x & 31;

    const float* Wih = dir ? Wih_b : Wih_f;
    const float* Whh = dir ? Whh_b : Whh_f;
    const float* bih = dir ? bih_b : bih_f;
    const float* bhh = dir ? bhh_b : bhh_f;
    float* hs = dir ? hsb : hsf;

    const int q = lane >> 4;
    const int u = lane & 15;
    const int R = q * 512 + g * 16 + u;

    // W_hh cols [wv*128,+128) of row R -> 128 VGPRs.
    float wh[128];
    {
        const float* base = Whh + (size_t)R * HDIM + wv * 128;
        #pragma unroll
        for (int i = 0; i < 32; ++i) {
            float4 v = *(const float4*)(base + 4 * i);
            wh[4*i] = v.x; wh[4*i+1] = v.y; wh[4*i+2] = v.z; wh[4*i+3] = v.w;
        }
    }
    // W_ih cols [wv*64,+64) of row R -> 64 VGPRs.
    float wx[64];
    {
        const float* base = Wih + (size_t)R * EDIM + wv * 64;
        #pragma unroll
        for (int i = 0; i < 16; ++i) {
            float4 v = *(const float4*)(base + 4 * i);
            wx[4*i] = v.x; wx[4*i+1] = v.y; wx[4*i+2] = v.z; wx[4*i+3] = v.w;
        }
    }
    // Per-wave finalize biases: lanes 0..3 own unit uu = g*16 + wv*4 + lane.
    float bi = 0.f, bff = 0.f, bgg = 0.f, boo = 0.f;
    if (lane < 4) {
        int uu = g * 16 + wv * 4 + lane;
        bi  = bih[uu]        + bhh[uu];
        bff = bih[512 + uu]  + bhh[512 + uu];
        bgg = bih[1024 + uu] + bhh[1024 + uu];
        boo = bih[1536 + uu] + bhh[1536 + uu];
    }

    __shared__ float pl[2][260];        // stride 65 between wave segments
    float c_state = 0.0f;               // valid on lanes 0..3 of each wave

    // Embedding value pipeline: lane holds emb[sent[t]][wv*64 + lane].
    float ecur;
    {
        int t0 = dir ? (T_LEN - 1) : 0;
        ecur = emb[(size_t)sent[t0] * EDIM + wv * 64 + lane];
    }

    for (int s = 0; s < T_LEN; ++s) {
        const int t = dir ? (T_LEN - 1 - s) : s;

        // Prefill the poll ring ASAP: 4 independent in-flight samples of this
        // wave's 8-byte flag word; they fly under enext + x-matvec.
        const unsigned long long* p = nullptr;
        unsigned long long r0 = 0, r1 = 0, r2 = 0, r3 = 0;
        if (s > 0) {
            const int tp = dir ? (t + 1) : (t - 1);
            p = (const unsigned long long*)(hs + (size_t)tp * HDIM + wv * 128) + lane;
            r0 = pollA(p); r1 = pollA(p); r2 = pollA(p); r3 = pollA(p);
        }
        // Prefetch next step's embedding value (h-independent).
        float enext = 0.0f;
        if (s + 1 < T_LEN) {
            int tn = dir ? (t - 1) : (t + 1);
            enext = emb[(size_t)sent[tn] * EDIM + wv * 64 + lane];
        }

        // x partial: 64 SGPR-broadcast MACs over 4 independent accumulators.
        float a0 = 0.f, a1 = 0.f, a2 = 0.f, a3 = 0.f;
        #pragma unroll
        for (int i = 0; i < 16; ++i) {
            a0 = fmaf(wx[4*i+0], rdlane(ecur, 4*i+0), a0);
            a1 = fmaf(wx[4*i+1], rdlane(ecur, 4*i+1), a1);
            a2 = fmaf(wx[4*i+2], rdlane(ecur, 4*i+2), a2);
            a3 = fmaf(wx[4*i+3], rdlane(ecur, 4*i+3), a3);
        }

        if (s > 0) {
            // Ring spin: test only the OLDEST sample (counted vmcnt wait),
            // shift, reissue. Steady-state sampling cadence ~ RT/4.
            while (bad2(r0)) {
                r0 = r1; r1 = r2; r2 = r3; r3 = pollA(p);
            }
            float h0 = u2f((unsigned)r0);
            float h1 = u2f((unsigned)(r0 >> 32));
            // h partial: 128 SGPR-broadcast MACs, 4 chains.
            #pragma unroll
            for (int i = 0; i < 32; ++i) {
                a0 = fmaf(wh[4*i+0], rdlane(h0, 2*i+0), a0);
                a1 = fmaf(wh[4*i+1], rdlane(h1, 2*i+0), a1);
                a2 = fmaf(wh[4*i+2], rdlane(h0, 2*i+1), a2);
                a3 = fmaf(wh[4*i+3], rdlane(h1, 2*i+1), a3);
            }
        }

        pl[s & 1][wv * 65 + lane] = (a0 + a1) + (a2 + a3);
        __syncthreads();

        // Wave-parallel finalize: wave wv handles units [g*16 + wv*4, +4).
        {
            const float* pb = pl[s & 1];
            const int idx = lane & 15;              // 4q + m over this wave's 4 units
            float val = pb[(lane >> 4) * 65 + (idx >> 2) * 16 + wv * 4 + (idx & 3)];
            val += __shfl_xor(val, 16, 64);         // reduce over column blocks
            val += __shfl_xor(val, 32, 64);
            const int m = lane & 3;
            float gi = __shfl(val, m,      64) + bi;
            float gf = __shfl(val, 4 + m,  64) + bff;
            float gg = __shfl(val, 8 + m,  64) + bgg;
            float go = __shfl(val, 12 + m, 64) + boo;
            if (lane < 4) {
                float iv = sigm(gi), fv = sigm(gf);
                float gv = tanh_fast(gg), ov = sigm(go);
                c_state = fv * c_state + iv * gv;
                float h = ov * tanh_fast(c_state);
                __hip_atomic_store(hs + (size_t)t * HDIM + g * 16 + wv * 4 + lane, h,
                                   __ATOMIC_RELAXED, __HIP_MEMORY_SCOPE_AGENT);
            }
        }
        ecur = enext;
    }
}

// ---------------------------------------------------------------------------
// tag_space[t] = [hs_f[t] | hs_b[t]] @ W_out^T + b_out  (f32 out)
// ---------------------------------------------------------------------------
__global__ __launch_bounds__(256) void out_gemm(
    const float* __restrict__ hsf, const float* __restrict__ hsb,
    const float* __restrict__ Wout, const float* __restrict__ bout,
    float* __restrict__ out)
{
    const int t   = blockIdx.x;
    const int tid = threadIdx.x;
    __shared__ float h2[1024];

    if (tid < 128)
        *(float4*)(h2 + tid * 4) = *(const float4*)(hsf + (size_t)t * HDIM + tid * 4);
    else
        *(float4*)(h2 + 512 + (tid - 128) * 4) = *(const float4*)(hsb + (size_t)t * HDIM + (tid - 128) * 4);
    __syncthreads();

    const int wv = tid >> 6, lane = tid & 63;
    for (int tag = wv; tag < NTAGS; tag += 4) {
        const float4* wr = (const float4*)(Wout + (size_t)tag * (2 * HDIM));
        float p = 0.0f;
        #pragma unroll
        for (int c = lane; c < 256; c += 64) {
            float4 wv4 = wr[c];
            float4 hv  = *(const float4*)(h2 + c * 4);
            p += wv4.x * hv.x + wv4.y * hv.y + wv4.z * hv.z + wv4.w * hv.w;
        }
        p += __shfl_down(p, 32, 64);
        p += __shfl_down(p, 16, 64);
        p += __shfl_down(p, 8, 64);
        p += __shfl_down(p, 4, 64);
        p += __shfl_down(p, 2, 64);
        p += __shfl_down(p, 1, 64);
        if (lane == 0) out[(size_t)t * NTAGS + tag] = p + bout[tag];
    }
}

// ---------------------------------------------------------------------------
extern "C" void kernel_launch(void* const* d_in, const int* in_sizes, int n_in,
                              void* d_out, int out_size, void* d_ws, size_t ws_size,
                              hipStream_t stream)
{
    const int*   sent  = (const int*)d_in[0];
    const float* emb   = (const float*)d_in[1];
    const float* Wih_f = (const float*)d_in[2];
    const float* Whh_f = (const float*)d_in[3];
    const float* bih_f = (const float*)d_in[4];
    const float* bhh_f = (const float*)d_in[5];
    const float* Wih_b = (const float*)d_in[6];
    const float* Whh_b = (const float*)d_in[7];
    const float* bih_b = (const float*)d_in[8];
    const float* bhh_b = (const float*)d_in[9];
    const float* Wout  = (const float*)d_in[10];
    const float* bout  = (const float*)d_in[11];
    float* out = (float*)d_out;

    char* ws = (char*)d_ws;
    // Workspace: hsf [4096*512 f32] @ 0 (8 MiB), hsb @ 8 MiB. Both double as
    // sync flags: sentinel-fill with 0xFF (-NaN, never produced by o*tanh(c)).
    float* hsf = (float*)(ws);
    float* hsb = (float*)(ws + 8388608);
    hipMemsetAsync(ws, 0xFF, 16777216, stream);

    lstm_scan<<<64, 256, 0, stream>>>(sent, emb,
                                      Wih_f, Whh_f, bih_f, bhh_f,
                                      Wih_b, Whh_b, bih_b, bhh_b,
                                      hsf, hsb);
    out_gemm<<<T_LEN, 256, 0, stream>>>(hsf, hsb, Wout, bout, out);
}

// Round 4
// 6102.522 us; speedup vs baseline: 2.9431x; 1.7844x over previous
//
#include <hip/hip_runtime.h>
#include <math.h>

#define T_LEN 4096
#define EDIM  256
#define HDIM  512
#define NTAGS 50
#define SENTW 0xFFFFFFFFu

__device__ __forceinline__ float sigm(float x) {
    return __builtin_amdgcn_rcpf(1.0f + __expf(-x));
}
__device__ __forceinline__ float tanh_fast(float x) {
    float e = __expf(2.0f * x);                       // x>>0 -> inf -> rcp=0 -> 1; x<<0 -> 0 -> -1
    return 1.0f - 2.0f * __builtin_amdgcn_rcpf(e + 1.0f);
}
__device__ __forceinline__ float u2f(unsigned u) { union { unsigned i; float f; } v; v.i = u; return v.f; }
__device__ __forceinline__ float rdlane(float v, int l) {
    union { float f; int i; } a, r;
    a.f = v;
    r.i = __builtin_amdgcn_readlane(a.i, l);   // SGPR broadcast, VALU-only
    return r.f;
}
// Poll as an atomic RMW (OR 0): executed AT the device coherence point (L3),
// so the flag line stays memory-side-cached instead of round-tripping HBM.
// Rounds 0-3 established: plain agent loads fetch from HBM (FETCH_SIZE ==
// poll traffic), and pipelining polls to one line is MSHR-merged (useless).
__device__ __forceinline__ unsigned long long pollA(unsigned long long* p) {
    return __hip_atomic_fetch_or(p, 0ull, __ATOMIC_RELAXED, __HIP_MEMORY_SCOPE_AGENT);
}
__device__ __forceinline__ bool bad2(unsigned long long v) {
    return ((unsigned)v == SENTW) || ((unsigned)(v >> 32) == SENTW);
}

// ---------------------------------------------------------------------------
// Persistent bidirectional LSTM scan (f32), data-as-flag sync, SGPR-broadcast
// matvec. Round-4 = round-0 skeleton (the proven-fastest structure: 64 WGs,
// round-robin placement, single-outstanding poll, wave0 finalize, one 64B
// h-store per block-step) with exactly three targeted changes:
//   (i)  sync via memory-side atomics: producer h-store = atomicExch,
//        consumer poll = atomicOr(p,0). Both RMW at the coherence point ->
//        flag lines live in L3, cutting both sync legs from HBM-class to
//        L3-class latency. (r0 counters showed store-through-to-HBM +
//        poll-fetch-from-HBM: WRITE_SIZE == h bytes, FETCH == poll bytes.)
//   (ii) 4 independent FMA accumulator chains (r0's single acc = 192-deep
//        dependent chain ~768 cy; now issue-bound ~512 cy).
//   (iii) fast __expf/rcp activations in the finalize (~400 -> ~150 cy tail).
// 64 WGs x 256 threads: blocks 0..31 forward, 32..63 backward.
// WG g owns hidden units [g*16,+16) => 64 gate rows. lane = row:
//   q = lane>>4 (gate i,f,g,o), u = lane&15, R = q*512 + g*16 + u.
// Wave wv owns column block: W_hh cols [wv*128,+128), W_ih cols [wv*64,+64).
// x-matvec executes under the first poll's RT shadow (already off the
// critical path); spin is single-outstanding (MSHR-merge lesson, r3).
// ---------------------------------------------------------------------------
__global__ __launch_bounds__(256, 1) void lstm_scan(
    const int* __restrict__ sent, const float* __restrict__ emb,
    const float* __restrict__ Wih_f, const float* __restrict__ Whh_f,
    const float* __restrict__ bih_f, const float* __restrict__ bhh_f,
    const float* __restrict__ Wih_b, const float* __restrict__ Whh_b,
    const float* __restrict__ bih_b, const float* __restrict__ bhh_b,
    float* hsf, float* hsb)
{
    const int tid  = threadIdx.x;
    const int lane = tid & 63;
    const int wv   = tid >> 6;          // wave id = column block
    const int dir  = blockIdx.x >> 5;
    const int g    = blockIdx.x & 31;

    const float* Wih = dir ? Wih_b : Wih_f;
    const float* Whh = dir ? Whh_b : Whh_f;
    const float* bih = dir ? bih_b : bih_f;
    const float* bhh = dir ? bhh_b : bhh_f;
    float* hs = dir ? hsb : hsf;

    const int q = lane >> 4;
    const int u = lane & 15;
    const int R = q * 512 + g * 16 + u;

    // W_hh cols [wv*128,+128) of row R -> 128 VGPRs.
    float wh[128];
    {
        const float* base = Whh + (size_t)R * HDIM + wv * 128;
        #pragma unroll
        for (int i = 0; i < 32; ++i) {
            float4 v = *(const float4*)(base + 4 * i);
            wh[4*i] = v.x; wh[4*i+1] = v.y; wh[4*i+2] = v.z; wh[4*i+3] = v.w;
        }
    }
    // W_ih cols [wv*64,+64) of row R -> 64 VGPRs.
    float wx[64];
    {
        const float* base = Wih + (size_t)R * EDIM + wv * 64;
        #pragma unroll
        for (int i = 0; i < 16; ++i) {
            float4 v = *(const float4*)(base + 4 * i);
            wx[4*i] = v.x; wx[4*i+1] = v.y; wx[4*i+2] = v.z; wx[4*i+3] = v.w;
        }
    }
    const float bias = bih[R] + bhh[R];

    __shared__ float pl[2][256];
    float c_state = 0.0f;

    // Embedding value pipeline: lane holds emb[sent[t]][wv*64 + lane].
    float ecur;
    {
        int t0 = dir ? (T_LEN - 1) : 0;
        ecur = emb[(size_t)sent[t0] * EDIM + wv * 64 + lane];
    }

    for (int s = 0; s < T_LEN; ++s) {
        const int t = dir ? (T_LEN - 1 - s) : s;

        // Issue first poll sample ASAP so it flies under the x-matvec.
        unsigned long long* p = nullptr;
        unsigned long long v = 0;
        if (s > 0) {
            const int tp = dir ? (t + 1) : (t - 1);
            p = (unsigned long long*)(hs + (size_t)tp * HDIM + wv * 128) + lane;
            v = pollA(p);
        }
        // Prefetch next step's embedding value (h-independent).
        float enext = 0.0f;
        if (s + 1 < T_LEN) {
            int tn = dir ? (t - 1) : (t + 1);
            enext = emb[(size_t)sent[tn] * EDIM + wv * 64 + lane];
        }

        // x partial: 64 SGPR-broadcast MACs over 4 independent accumulators
        // (hidden under the in-flight first poll).
        float a0 = 0.f, a1 = 0.f, a2 = 0.f, a3 = 0.f;
        #pragma unroll
        for (int i = 0; i < 16; ++i) {
            a0 = fmaf(wx[4*i+0], rdlane(ecur, 4*i+0), a0);
            a1 = fmaf(wx[4*i+1], rdlane(ecur, 4*i+1), a1);
            a2 = fmaf(wx[4*i+2], rdlane(ecur, 4*i+2), a2);
            a3 = fmaf(wx[4*i+3], rdlane(ecur, 4*i+3), a3);
        }

        if (s > 0) {
            // Single-outstanding spin (r3 lesson: pipelined same-line polls
            // MSHR-merge into stale snapshots).
            while (bad2(v)) v = pollA(p);
            float h0 = u2f((unsigned)v);
            float h1 = u2f((unsigned)(v >> 32));
            // h partial: 128 SGPR-broadcast MACs, 4 chains.
            #pragma unroll
            for (int i = 0; i < 32; ++i) {
                a0 = fmaf(wh[4*i+0], rdlane(h0, 2*i+0), a0);
                a1 = fmaf(wh[4*i+1], rdlane(h1, 2*i+0), a1);
                a2 = fmaf(wh[4*i+2], rdlane(h0, 2*i+1), a2);
                a3 = fmaf(wh[4*i+3], rdlane(h1, 2*i+1), a3);
            }
        }

        pl[s & 1][wv * 64 + lane] = (a0 + a1) + (a2 + a3);
        __syncthreads();

        // wave0 finalize (r0 structure), fast activations, one 16-lane
        // atomicExch wave-op = single 64B-line h publish at the L3.
        if (wv == 0) {
            const float* pb = pl[s & 1];
            float tot = pb[lane] + pb[64 + lane] + pb[128 + lane] + pb[192 + lane] + bias;
            float gi = __shfl(tot, u,      64);
            float gf = __shfl(tot, u + 16, 64);
            float gg = __shfl(tot, u + 32, 64);
            float go = __shfl(tot, u + 48, 64);
            if (lane < 16) {
                float iv = sigm(gi), fv = sigm(gf);
                float gv = tanh_fast(gg), ov = sigm(go);
                c_state = fv * c_state + iv * gv;
                float h = ov * tanh_fast(c_state);
                __hip_atomic_exchange(hs + (size_t)t * HDIM + g * 16 + u, h,
                                      __ATOMIC_RELAXED, __HIP_MEMORY_SCOPE_AGENT);
            }
        }
        ecur = enext;
    }
}

// ---------------------------------------------------------------------------
// tag_space[t] = [hs_f[t] | hs_b[t]] @ W_out^T + b_out  (f32 out)
// ---------------------------------------------------------------------------
__global__ __launch_bounds__(256) void out_gemm(
    const float* __restrict__ hsf, const float* __restrict__ hsb,
    const float* __restrict__ Wout, const float* __restrict__ bout,
    float* __restrict__ out)
{
    const int t   = blockIdx.x;
    const int tid = threadIdx.x;
    __shared__ float h2[1024];

    if (tid < 128)
        *(float4*)(h2 + tid * 4) = *(const float4*)(hsf + (size_t)t * HDIM + tid * 4);
    else
        *(float4*)(h2 + 512 + (tid - 128) * 4) = *(const float4*)(hsb + (size_t)t * HDIM + (tid - 128) * 4);
    __syncthreads();

    const int wv = tid >> 6, lane = tid & 63;
    for (int tag = wv; tag < NTAGS; tag += 4) {
        const float4* wr = (const float4*)(Wout + (size_t)tag * (2 * HDIM));
        float p = 0.0f;
        #pragma unroll
        for (int c = lane; c < 256; c += 64) {
            float4 wv4 = wr[c];
            float4 hv  = *(const float4*)(h2 + c * 4);
            p += wv4.x * hv.x + wv4.y * hv.y + wv4.z * hv.z + wv4.w * hv.w;
        }
        p += __shfl_down(p, 32, 64);
        p += __shfl_down(p, 16, 64);
        p += __shfl_down(p, 8, 64);
        p += __shfl_down(p, 4, 64);
        p += __shfl_down(p, 2, 64);
        p += __shfl_down(p, 1, 64);
        if (lane == 0) out[(size_t)t * NTAGS + tag] = p + bout[tag];
    }
}

// ---------------------------------------------------------------------------
extern "C" void kernel_launch(void* const* d_in, const int* in_sizes, int n_in,
                              void* d_out, int out_size, void* d_ws, size_t ws_size,
                              hipStream_t stream)
{
    const int*   sent  = (const int*)d_in[0];
    const float* emb   = (const float*)d_in[1];
    const float* Wih_f = (const float*)d_in[2];
    const float* Whh_f = (const float*)d_in[3];
    const float* bih_f = (const float*)d_in[4];
    const float* bhh_f = (const float*)d_in[5];
    const float* Wih_b = (const float*)d_in[6];
    const float* Whh_b = (const float*)d_in[7];
    const float* bih_b = (const float*)d_in[8];
    const float* bhh_b = (const float*)d_in[9];
    const float* Wout  = (const float*)d_in[10];
    const float* bout  = (const float*)d_in[11];
    float* out = (float*)d_out;

    char* ws = (char*)d_ws;
    // Workspace: hsf [4096*512 f32] @ 0 (8 MiB), hsb @ 8 MiB. Both double as
    // sync flags: sentinel-fill with 0xFF (-NaN, never produced by o*tanh(c)).
    float* hsf = (float*)(ws);
    float* hsb = (float*)(ws + 8388608);
    hipMemsetAsync(ws, 0xFF, 16777216, stream);

    lstm_scan<<<64, 256, 0, stream>>>(sent, emb,
                                      Wih_f, Whh_f, bih_f, bhh_f,
                                      Wih_b, Whh_b, bih_b, bhh_b,
                                      hsf, hsb);
    out_gemm<<<T_LEN, 256, 0, stream>>>(hsf, hsb, Wout, bout, out);
}